// Round 8
// baseline (2186.512 us; speedup 1.0000x reference)
//
#include <hip/hip_runtime.h>
#include <cstdint>
#include <cstddef>

// ---------------------------------------------------------------------------
// Sememe-LSTM, T=256 B=64 I=M=512.
// Phase A: one f16 MFMA GEMM [16384,1024] @ [1024,2560] computing every
//          non-recurrent term; epilogue stores f16 pre[t][g][m][b] and
//          addc[t][m][b] (= sigmoid(fs_raw)*sememe_c, fully precomputable).
// Phase B: persistent 64-WG kernel, 256 serial steps.
//   R1/R2: AGENT acquire/release emit buffer_inv/buffer_wbl2 -> never in loop.
//   R4:    flags + producer drain + syncthreads + poll + gather = 4.56us/step.
//   R5:    sc0-only is L1-served (workgroup scope) -> hang. Use sc0+sc1.
//   R6/R7: tags-only (no flags): retry unit = full 64KB coherent gather ->
//          drifting WGs spin full gathers -> contention spiral (FETCH +174MB,
//          6.8-7.6us/step).
//   R8:    HYBRID. Tagged h (2 mantissa LSBs = step&3) + per-WAVE flags as a
//          cheap hint. Producer wave: issue h stores, issue own flag — NO
//          drain, NO syncthreads. Consumer: poll flags (1 dwordx4/lane
//          covering one WG's 4 wave-flags) until >= t, then ONE tagged
//          gather; tag-mismatch regather only in the rare flag-overtakes-h
//          window. Induction: every step validates every location, pinning
//          the coherence point >= step t-2 -> mod-4 tags sufficient; replay
//          residue killed by t=0/1 full validation + flag memset.
// ---------------------------------------------------------------------------

typedef _Float16 half8 __attribute__((ext_vector_type(8)));
typedef _Float16 half4 __attribute__((ext_vector_type(4)));
typedef float    f32x4 __attribute__((ext_vector_type(4)));
typedef unsigned int uint32x4 __attribute__((ext_vector_type(4)));

#define T_STEPS 256
#define B_DIM   64
#define M_DIM   512
#define KA      1024          // combined K (x | sememe_h)
#define NA      2560          // combined N (iou 1536 | f 512 | fs 512)
#define MA      16384         // T*B
#define NWG_REC 64

__device__ __forceinline__ float sigmoidf_fast(float x) {
    return 1.0f / (1.0f + __expf(-x));
}
__device__ __forceinline__ float tanhf_fast(float x) {
    float e = __expf(2.0f * x);
    return 1.0f - 2.0f / (e + 1.0f);
}

// ---------------- conversion kernels (f32 -> f16 packing) -------------------

__global__ void conv_xs(const float* __restrict__ inp, const float* __restrict__ sh,
                        _Float16* __restrict__ xs) {
    int idx = blockIdx.x * blockDim.x + threadIdx.x;   // one 8-elem chunk
    const int total = MA * KA / 8;
    if (idx >= total) return;
    int row = idx >> 7;
    int col = (idx & 127) * 8;
    const float* src = (col < 512) ? (inp + (size_t)row * 512 + col)
                                   : (sh  + (size_t)row * 512 + (col - 512));
    f32x4 a = *(const f32x4*)src;
    f32x4 b = *(const f32x4*)(src + 4);
    half8 o;
    o[0]=(_Float16)a[0]; o[1]=(_Float16)a[1]; o[2]=(_Float16)a[2]; o[3]=(_Float16)a[3];
    o[4]=(_Float16)b[0]; o[5]=(_Float16)b[1]; o[6]=(_Float16)b[2]; o[7]=(_Float16)b[3];
    *(half8*)(xs + (size_t)idx * 8) = o;
}

__global__ void conv_w(const float* __restrict__ W_ioux, const float* __restrict__ W_ious,
                       const float* __restrict__ W_fx,   const float* __restrict__ W_fxs,
                       const float* __restrict__ W_fs,   _Float16* __restrict__ wc) {
    int idx = blockIdx.x * blockDim.x + threadIdx.x;
    const int total = NA * KA / 8;
    if (idx >= total) return;
    int n = idx >> 7;
    int col = (idx & 127) * 8;
    const float* src = nullptr;
    if (col < 512) {
        int k = col;
        src = (n < 1536) ? (W_ioux + (size_t)n * 512 + k)
            : (n < 2048) ? (W_fx   + (size_t)(n - 1536) * 512 + k)
                         : (W_fxs  + (size_t)(n - 2048) * 512 + k);
    } else {
        int k = col - 512;
        if (n < 1536)      src = W_ious + (size_t)n * 512 + k;
        else if (n >= 2048) src = W_fs  + (size_t)(n - 2048) * 512 + k;
        // else: zero block (f gate has no sememe term)
    }
    half8 o;
    if (src) {
        f32x4 a = *(const f32x4*)src;
        f32x4 b = *(const f32x4*)(src + 4);
        o[0]=(_Float16)a[0]; o[1]=(_Float16)a[1]; o[2]=(_Float16)a[2]; o[3]=(_Float16)a[3];
        o[4]=(_Float16)b[0]; o[5]=(_Float16)b[1]; o[6]=(_Float16)b[2]; o[7]=(_Float16)b[3];
    } else {
        #pragma unroll
        for (int i = 0; i < 8; ++i) o[i] = (_Float16)0.0f;
    }
    *(half8*)(wc + (size_t)idx * 8) = o;
}

__global__ void conv_wr(const float* __restrict__ W_iouh, const float* __restrict__ W_fh,
                        _Float16* __restrict__ wr) {
    int idx = blockIdx.x * blockDim.x + threadIdx.x;
    const int total = 2048 * 512 / 8;
    if (idx >= total) return;
    int n = idx >> 6;
    int col = (idx & 63) * 8;
    int wgs = n >> 5, loc = n & 31;
    int g = (loc >> 4) * 2 + ((loc >> 3) & 1);
    int m = wgs * 8 + (loc & 7);
    const float* src = (g < 3) ? (W_iouh + ((size_t)(g * 512 + m)) * 512 + col)
                               : (W_fh   + (size_t)m * 512 + col);
    f32x4 a = *(const f32x4*)src;
    f32x4 b = *(const f32x4*)(src + 4);
    half8 o;
    o[0]=(_Float16)a[0]; o[1]=(_Float16)a[1]; o[2]=(_Float16)a[2]; o[3]=(_Float16)a[3];
    o[4]=(_Float16)b[0]; o[5]=(_Float16)b[1]; o[6]=(_Float16)b[2]; o[7]=(_Float16)b[3];
    *(half8*)(wr + (size_t)idx * 8) = o;
}

// h0 -> f16 with 2 LSBs cleared (epoch tag 0): buf0[b][m]
__global__ void conv_h0(const float* __restrict__ h0, unsigned short* __restrict__ hb) {
    int idx = blockIdx.x * blockDim.x + threadIdx.x;
    const int total = B_DIM * M_DIM / 8;
    if (idx >= total) return;
    f32x4 a = *(const f32x4*)(h0 + (size_t)idx * 8);
    f32x4 b = *(const f32x4*)(h0 + (size_t)idx * 8 + 4);
    unsigned short o[8];
    #pragma unroll
    for (int j = 0; j < 4; ++j) {
        _Float16 ha = (_Float16)a[j], hbv = (_Float16)b[j];
        o[j]     = (unsigned short)(__builtin_bit_cast(unsigned short, ha)  & 0xFFFCu);
        o[j + 4] = (unsigned short)(__builtin_bit_cast(unsigned short, hbv) & 0xFFFCu);
    }
    uint32x4 pk;
    pk[0] = o[0] | ((unsigned)o[1] << 16);
    pk[1] = o[2] | ((unsigned)o[3] << 16);
    pk[2] = o[4] | ((unsigned)o[5] << 16);
    pk[3] = o[6] | ((unsigned)o[7] << 16);
    *(uint32x4*)(hb + (size_t)idx * 8) = pk;
}

// ---------------- Phase A: big GEMM + fused epilogue ------------------------

__global__ __launch_bounds__(256, 2)
void gemm_pre(const _Float16* __restrict__ A, const _Float16* __restrict__ W,
              const float* __restrict__ b_ioux, const float* __restrict__ b_iouh,
              const float* __restrict__ b_ious, const float* __restrict__ b_fx,
              const float* __restrict__ b_fh,   const float* __restrict__ b_fxs,
              const float* __restrict__ b_fs,   const float* __restrict__ smc,
              _Float16* __restrict__ pre, _Float16* __restrict__ addc) {
    __shared__ _Float16 As[128 * 64];
    __shared__ _Float16 Bs[128 * 64];

    const int nwg = 2560;
    int orig = blockIdx.x;
    int wgid = (orig & 7) * (nwg >> 3) + (orig >> 3);   // XCD-aware swizzle (2560%8==0)
    const int bx = wgid & 127;       // M tile (128 of them)
    const int by = wgid >> 7;        // N tile (20)
    const int m0 = bx * 128, n0 = by * 128;

    const int tid = threadIdx.x;
    const int wv = tid >> 6, lane = tid & 63;
    const int lr = lane & 15, lq = lane >> 4;
    const int wr = wv >> 1, wc = wv & 1;

    f32x4 acc[4][4];
    #pragma unroll
    for (int i = 0; i < 4; ++i)
        #pragma unroll
        for (int j = 0; j < 4; ++j)
            #pragma unroll
            for (int r = 0; r < 4; ++r) acc[i][j][r] = 0.0f;

    for (int kt = 0; kt < KA / 64; ++kt) {
        const int k0 = kt * 64;
        #pragma unroll
        for (int j = 0; j < 4; ++j) {
            int L = j * 4096 + wv * 1024 + lane * 16;       // linear LDS byte
            int row = L >> 7;
            int colb = (L & 127) ^ ((row & 7) << 4);        // inverse-swizzled source
            const char* ga = (const char*)(A + (size_t)(m0 + row) * KA + k0) + colb;
            __builtin_amdgcn_global_load_lds(
                (const __attribute__((address_space(1))) void*)ga,
                (__attribute__((address_space(3))) void*)((char*)As + j * 4096 + wv * 1024),
                16, 0, 0);
            const char* gb = (const char*)(W + (size_t)(n0 + row) * KA + k0) + colb;
            __builtin_amdgcn_global_load_lds(
                (const __attribute__((address_space(1))) void*)gb,
                (__attribute__((address_space(3))) void*)((char*)Bs + j * 4096 + wv * 1024),
                16, 0, 0);
        }
        __syncthreads();

        half8 af[4][2], bf[4][2];
        #pragma unroll
        for (int f = 0; f < 4; ++f) {
            #pragma unroll
            for (int kk = 0; kk < 2; ++kk) {
                {
                    int row = wr * 64 + f * 16 + lr;
                    int byt = row * 128 + (((kk * 32 + lq * 8) * 2) ^ ((row & 7) << 4));
                    af[f][kk] = *(const half8*)((const char*)As + byt);
                }
                {
                    int row = wc * 64 + f * 16 + lr;
                    int byt = row * 128 + (((kk * 32 + lq * 8) * 2) ^ ((row & 7) << 4));
                    bf[f][kk] = *(const half8*)((const char*)Bs + byt);
                }
            }
        }
        #pragma unroll
        for (int kk = 0; kk < 2; ++kk)
            #pragma unroll
            for (int fi = 0; fi < 4; ++fi)
                #pragma unroll
                for (int fj = 0; fj < 4; ++fj)
                    acc[fi][fj] = __builtin_amdgcn_mfma_f32_16x16x32_f16(
                        af[fi][kk], bf[fj][kk], acc[fi][fj], 0, 0, 0);
        __syncthreads();
    }

    // Epilogue: D layout col=lane&15, row=(lane>>4)*4+reg.
    #pragma unroll
    for (int fi = 0; fi < 4; ++fi) {
        int row0 = m0 + wr * 64 + fi * 16 + lq * 4;  // 4 consecutive tb rows
        int tt = row0 >> 6;
        int b  = row0 & 63;
        #pragma unroll
        for (int fj = 0; fj < 4; ++fj) {
            int col = n0 + wc * 64 + fj * 16 + lr;
            f32x4 v = acc[fi][fj];
            if (col < 2048) {
                int g, mm; float bias;
                if (col < 1536) { g = col >> 9; mm = col & 511;
                                  bias = b_ioux[col] + b_iouh[col] + b_ious[col]; }
                else            { g = 3; mm = col - 1536; bias = b_fx[mm] + b_fh[mm]; }
                half4 hv;
                #pragma unroll
                for (int r = 0; r < 4; ++r) hv[r] = (_Float16)(v[r] + bias);
                *(half4*)(pre + ((((size_t)tt * 4 + g) * 512 + mm) * 64 + b)) = hv;
            } else {
                int mm = col - 2048;
                float bias = b_fxs[mm] + b_fs[mm];
                half4 hv;
                #pragma unroll
                for (int r = 0; r < 4; ++r) {
                    float s  = sigmoidf_fast(v[r] + bias);
                    float sc = smc[((size_t)(tt * 64 + b + r)) * 512 + mm];
                    hv[r] = (_Float16)(s * sc);
                }
                *(half4*)(addc + (((size_t)tt * 512 + mm) * 64 + b)) = hv;
            }
        }
    }
}

// ---------------- Phase B: persistent recurrent kernel ----------------------
// 64 WGs x 256 threads, no syncthreads/drain in the loop. WG owns m in
// [wg*8,+8); wave v owns b-tile [v*16,+16). Lane l: c8=(l>>3)&1 splits lane
// pairs l / l^8 into (i,u)/(o,f). Weights in registers.
// h transport: f16, tag (step&3) in 2 mantissa LSBs, parity double buffer,
// sc0+sc1. Per-WAVE flags (hint): flags[wg*4+wv]=t+1 stored right after the
// wave's h stores issue. Consumer: cheap flag poll (dwordx4/lane = WG lane's
// 4 wave flags) until >= t, then ONE tagged gather; regather if tags stale.

__global__ __launch_bounds__(256, 1)
void lstm_rec(const _Float16* __restrict__ Wr, const _Float16* __restrict__ pre,
              const _Float16* __restrict__ addc, const float* __restrict__ c0,
              unsigned short* __restrict__ hbuf, float* __restrict__ out,
              int* __restrict__ flags) {
    const int wg = blockIdx.x;
    const int tid = threadIdx.x;
    const int wv = tid >> 6, lane = tid & 63;
    const int lr = lane & 15, lq = lane >> 4;
    const int c8 = (lane >> 3) & 1;
    const int m  = wg * 8 + (lane & 7);
    const int b0 = wv * 16 + lq * 4;

    // recurrent weights -> registers (once)
    half8 bfr[2][16];
    #pragma unroll
    for (int nt = 0; nt < 2; ++nt)
        #pragma unroll
        for (int kk = 0; kk < 16; ++kk)
            bfr[nt][kk] = *(const half8*)(Wr + ((size_t)(wg * 32 + nt * 16 + lr)) * 512
                                          + kk * 32 + lq * 8);

    float c[4];
    #pragma unroll
    for (int r = 0; r < 4; ++r) c[r] = c0[(size_t)(b0 + r) * 512 + m];

    half4 pv[2], av;
    #pragma unroll
    for (int nt = 0; nt < 2; ++nt) {
        int g = nt * 2 + c8;
        pv[nt] = *(const half4*)(pre + (((size_t)0 * 4 + g) * 512 + m) * 64 + b0);
    }
    av = *(const half4*)(addc + ((size_t)0 * 512 + m) * 64 + b0);

    // per-lane gather base: row = wv*16+lr, col-base = lq*8 (f16, 2B)
    const size_t rowoff = ((size_t)(wv * 16 + lr) * 512 + lq * 8) * 2;
    const int* fp = flags + lane * 4;        // WG `lane`'s 4 wave-flags

    for (int t = 0; t < T_STEPS; ++t) {
        const char* bp = (const char*)hbuf + (size_t)(t & 1) * 65536 + rowoff;
        const unsigned pat = (unsigned)(t & 3) * 0x00010001u;   // expected LSB tag

        // acc init from CURRENT step's pre/addc — BEFORE prefetch clobbers
        f32x4 acc[2];
        #pragma unroll
        for (int nt = 0; nt < 2; ++nt)
            #pragma unroll
            for (int r = 0; r < 4; ++r) acc[nt][r] = (float)pv[nt][r];
        half4 avc = av;

        // prefetch next step's pre/addc (cached; completes under poll/gather)
        if (t + 1 < T_STEPS) {
            #pragma unroll
            for (int nt = 0; nt < 2; ++nt) {
                int g = nt * 2 + c8;
                pv[nt] = *(const half4*)(pre + (((size_t)(t + 1) * 4 + g) * 512 + m) * 64 + b0);
            }
            av = *(const half4*)(addc + ((size_t)(t + 1) * 512 + m) * 64 + b0);
        }

        // ---- cheap flag poll: all 256 wave-flags >= t (hint only) ----
        while (true) {
            uint32x4 fv;
            asm volatile("global_load_dwordx4 %0, %1, off sc0 sc1\n\t"
                         "s_waitcnt vmcnt(0)"
                         : "=v"(fv) : "v"(fp) : "memory");
            bool ok = ((int)fv[0] >= t) & ((int)fv[1] >= t) &
                      ((int)fv[2] >= t) & ((int)fv[3] >= t);
            if (__all(ok)) break;
            __builtin_amdgcn_s_sleep(1);
        }

        // ---- ONE tagged gather (regather only if flag overtook h stores) ----
        half8 af[16];
        while (true) {
            asm volatile(
                "global_load_dwordx4 %0,  %16, off sc0 sc1\n\t"
                "global_load_dwordx4 %1,  %16, off offset:64 sc0 sc1\n\t"
                "global_load_dwordx4 %2,  %16, off offset:128 sc0 sc1\n\t"
                "global_load_dwordx4 %3,  %16, off offset:192 sc0 sc1\n\t"
                "global_load_dwordx4 %4,  %16, off offset:256 sc0 sc1\n\t"
                "global_load_dwordx4 %5,  %16, off offset:320 sc0 sc1\n\t"
                "global_load_dwordx4 %6,  %16, off offset:384 sc0 sc1\n\t"
                "global_load_dwordx4 %7,  %16, off offset:448 sc0 sc1\n\t"
                "global_load_dwordx4 %8,  %16, off offset:512 sc0 sc1\n\t"
                "global_load_dwordx4 %9,  %16, off offset:576 sc0 sc1\n\t"
                "global_load_dwordx4 %10, %16, off offset:640 sc0 sc1\n\t"
                "global_load_dwordx4 %11, %16, off offset:704 sc0 sc1\n\t"
                "global_load_dwordx4 %12, %16, off offset:768 sc0 sc1\n\t"
                "global_load_dwordx4 %13, %16, off offset:832 sc0 sc1\n\t"
                "global_load_dwordx4 %14, %16, off offset:896 sc0 sc1\n\t"
                "global_load_dwordx4 %15, %16, off offset:960 sc0 sc1\n\t"
                "s_waitcnt vmcnt(0)"
                : "=&v"(af[0]),  "=&v"(af[1]),  "=&v"(af[2]),  "=&v"(af[3]),
                  "=&v"(af[4]),  "=&v"(af[5]),  "=&v"(af[6]),  "=&v"(af[7]),
                  "=&v"(af[8]),  "=&v"(af[9]),  "=&v"(af[10]), "=&v"(af[11]),
                  "=&v"(af[12]), "=&v"(af[13]), "=&v"(af[14]), "=&v"(af[15])
                : "v"(bp)
                : "memory");
            unsigned bad = 0;
            #pragma unroll
            for (int j = 0; j < 16; ++j) {
                uint32x4 dv = __builtin_bit_cast(uint32x4, af[j]);
                #pragma unroll
                for (int d = 0; d < 4; ++d)
                    bad |= (dv[d] & 0x00030003u) ^ pat;
            }
            if (__all(bad == 0)) break;
            __builtin_amdgcn_s_sleep(1);
        }

        #pragma unroll
        for (int kk = 0; kk < 16; ++kk) {
            acc[0] = __builtin_amdgcn_mfma_f32_16x16x32_f16(af[kk], bfr[0][kk], acc[0], 0, 0, 0);
            acc[1] = __builtin_amdgcn_mfma_f32_16x16x32_f16(af[kk], bfr[1][kk], acc[1], 0, 0, 0);
        }

        float hnew[4];
        #pragma unroll
        for (int r = 0; r < 4; ++r) {
            float raw0 = acc[0][r];   // laneA: i_raw  | laneB: o_raw
            float raw1 = acc[1][r];   // laneA: u_raw  | laneB: f_raw
            float s0 = sigmoidf_fast(raw0);
            float v1 = c8 ? sigmoidf_fast(raw1) : tanhf_fast(raw1);
            float sf = __shfl_xor(v1, 8);               // laneA <- sig(f)
            float cn = s0 * v1 + sf * c[r] + (float)avc[r];   // valid on laneA
            float tc = tanhf_fast(cn);
            float tcx = __shfl_xor(tc, 8);              // laneB <- tanh(c_new)
            if (!c8) c[r] = cn;
            hnew[r] = s0 * tcx;                         // valid on laneB
        }

        if (t == T_STEPS - 1) {
            if (c8) {
                #pragma unroll
                for (int r = 0; r < 4; ++r)
                    out[((size_t)t * B_DIM + b0 + r) * M_DIM + m] = hnew[r];
            }
            size_t base = (size_t)T_STEPS * B_DIM * M_DIM;
            if (!c8) {
                #pragma unroll
                for (int r = 0; r < 4; ++r)
                    out[base + (size_t)(b0 + r) * M_DIM + m] = c[r];
            } else {
                #pragma unroll
                for (int r = 0; r < 4; ++r)
                    out[base + (size_t)B_DIM * M_DIM + (size_t)(b0 + r) * M_DIM + m] = hnew[r];
            }
        } else {
            // publish h^{t+1}: tagged f16 stores, then THIS WAVE's flag.
            // No drain, no syncthreads — tags catch flag-overtakes-h.
            unsigned short* hw = hbuf + (size_t)((t + 1) & 1) * 32768;
            const unsigned tag1 = (unsigned)((t + 1) & 3);
            if (c8) {
                #pragma unroll
                for (int r = 0; r < 4; ++r) {
                    _Float16 hv = (_Float16)hnew[r];
                    unsigned u = ((unsigned)__builtin_bit_cast(unsigned short, hv)
                                  & 0xFFFCu) | tag1;
                    asm volatile("global_store_short %0, %1, off sc0 sc1"
                                 :: "v"(hw + (size_t)(b0 + r) * 512 + m), "v"(u)
                                 : "memory");
                }
            }
            if (lane == 0) {
                unsigned fv = (unsigned)(t + 1);
                asm volatile("global_store_dword %0, %1, off sc0 sc1"
                             :: "v"(flags + wg * 4 + wv), "v"(fv) : "memory");
            }
            // out[t] stores drain during next poll (normal cached)
            if (c8) {
                #pragma unroll
                for (int r = 0; r < 4; ++r)
                    out[((size_t)t * B_DIM + b0 + r) * M_DIM + m] = hnew[r];
            }
        }
    }
}

// ---------------------------------------------------------------------------

extern "C" void kernel_launch(void* const* d_in, const int* in_sizes, int n_in,
                              void* d_out, int out_size, void* d_ws, size_t ws_size,
                              hipStream_t stream) {
    const float* inputs  = (const float*)d_in[0];
    const float* smc     = (const float*)d_in[1];
    const float* smh     = (const float*)d_in[2];
    const float* c0      = (const float*)d_in[3];
    const float* h0      = (const float*)d_in[4];
    const float* W_ioux  = (const float*)d_in[5];
    const float* b_ioux  = (const float*)d_in[6];
    const float* W_iouh  = (const float*)d_in[7];
    const float* b_iouh  = (const float*)d_in[8];
    const float* W_ious  = (const float*)d_in[9];
    const float* b_ious  = (const float*)d_in[10];
    const float* W_fx    = (const float*)d_in[11];
    const float* b_fx    = (const float*)d_in[12];
    const float* W_fxs   = (const float*)d_in[13];
    const float* b_fxs   = (const float*)d_in[14];
    const float* W_fh    = (const float*)d_in[15];
    const float* b_fh    = (const float*)d_in[16];
    const float* W_fs    = (const float*)d_in[17];
    const float* b_fs    = (const float*)d_in[18];

    char* ws = (char*)d_ws;
    size_t off = 0;
    auto alloc = [&](size_t bytes) {
        char* p = ws + off;
        off = (off + bytes + 255) & ~(size_t)255;
        return p;
    };
    _Float16* XS   = (_Float16*)alloc((size_t)MA * KA * 2);          // 32 MiB
    _Float16* Wc   = (_Float16*)alloc((size_t)NA * KA * 2);          // 5 MiB
    _Float16* Wr   = (_Float16*)alloc((size_t)2048 * 512 * 2);       // 2 MiB
    unsigned short* hb = (unsigned short*)alloc((size_t)2 * B_DIM * M_DIM * 2); // 128 KiB
    _Float16* pre  = (_Float16*)alloc((size_t)T_STEPS * 4 * 512 * 64 * 2); // 64 MiB
    _Float16* addc = (_Float16*)alloc((size_t)T_STEPS * 512 * 64 * 2);     // 16 MiB
    int* flags     = (int*)alloc(256 * sizeof(int));                       // 1 KiB
    if (off > ws_size) return;  // insufficient workspace -> visible failure

    hipMemsetAsync(flags, 0, 256 * sizeof(int), stream);
    conv_xs <<<MA * KA / 8 / 256, 256, 0, stream>>>(inputs, smh, XS);
    conv_w  <<<NA * KA / 8 / 256, 256, 0, stream>>>(W_ioux, W_ious, W_fx, W_fxs, W_fs, Wc);
    conv_wr <<<2048 * 512 / 8 / 256, 256, 0, stream>>>(W_iouh, W_fh, Wr);
    conv_h0 <<<B_DIM * M_DIM / 8 / 256, 256, 0, stream>>>(h0, hb);
    gemm_pre<<<2560, 256, 0, stream>>>(XS, Wc, b_ioux, b_iouh, b_ious, b_fx, b_fh,
                                       b_fxs, b_fs, smc, pre, addc);
    lstm_rec<<<NWG_REC, 256, 0, stream>>>(Wr, pre, addc, c0, hb, (float*)d_out, flags);
}

// Round 9
// 1399.097 us; speedup vs baseline: 1.5628x; 1.5628x over previous
//
#include <hip/hip_runtime.h>
#include <cstdint>
#include <cstddef>

// ---------------------------------------------------------------------------
// Sememe-LSTM, T=256 B=64 I=M=512.
// Phase A: one f16 MFMA GEMM [16384,1024] @ [1024,2560] computing every
//          non-recurrent term; epilogue stores f16 pre[t][g][m][b] and
//          addc[t][m][b] (= sigmoid(fs_raw)*sememe_c, fully precomputable).
// Phase B: persistent 64-WG kernel, 256 serial steps.
//   R1/R2: AGENT acquire/release emit buffer_inv/buffer_wbl2 -> never in loop.
//   R4:    drain + syncthreads + flag + poll + gather = 4.56us/step (best).
//   R5:    sc0-only / XCD pinning -> hang. Device traffic MUST be sc0+sc1.
//   R6/R7: tags-only, no flags/drain: unbounded WG drift -> full-gather
//          retry spiral (6.8-7.6us/step, FETCH +174MB).
//   R8:    flags w/o drain: flag (1 dword) commits before 64 h-stores ->
//          "flag overtakes h" is the COMMON case -> 7.8us/step.
//   R9:    R4 producer (tagged h stores + vmcnt(0) drain + syncthreads +
//          per-WG flag) + SPECULATIVE tagged gather consumer: gather first,
//          validate 2-LSB epoch tags (step&3); hit -> poll RT eliminated.
//          Miss -> flag-poll backstop (drain-before-flag guarantees the
//          post-poll regather is fresh; no spiral). Worst case = R4 + one
//          wasted gather; common case saves ~1.3us/step.
// ---------------------------------------------------------------------------

typedef _Float16 half8 __attribute__((ext_vector_type(8)));
typedef _Float16 half4 __attribute__((ext_vector_type(4)));
typedef float    f32x4 __attribute__((ext_vector_type(4)));
typedef unsigned int uint32x4 __attribute__((ext_vector_type(4)));

#define T_STEPS 256
#define B_DIM   64
#define M_DIM   512
#define KA      1024          // combined K (x | sememe_h)
#define NA      2560          // combined N (iou 1536 | f 512 | fs 512)
#define MA      16384         // T*B
#define NWG_REC 64
#define FLAG_STRIDE 32        // ints -> 128B per flag line

__device__ __forceinline__ float sigmoidf_fast(float x) {
    return 1.0f / (1.0f + __expf(-x));
}
__device__ __forceinline__ float tanhf_fast(float x) {
    float e = __expf(2.0f * x);
    return 1.0f - 2.0f / (e + 1.0f);
}

// ---------------- conversion kernels (f32 -> f16 packing) -------------------

__global__ void conv_xs(const float* __restrict__ inp, const float* __restrict__ sh,
                        _Float16* __restrict__ xs) {
    int idx = blockIdx.x * blockDim.x + threadIdx.x;   // one 8-elem chunk
    const int total = MA * KA / 8;
    if (idx >= total) return;
    int row = idx >> 7;
    int col = (idx & 127) * 8;
    const float* src = (col < 512) ? (inp + (size_t)row * 512 + col)
                                   : (sh  + (size_t)row * 512 + (col - 512));
    f32x4 a = *(const f32x4*)src;
    f32x4 b = *(const f32x4*)(src + 4);
    half8 o;
    o[0]=(_Float16)a[0]; o[1]=(_Float16)a[1]; o[2]=(_Float16)a[2]; o[3]=(_Float16)a[3];
    o[4]=(_Float16)b[0]; o[5]=(_Float16)b[1]; o[6]=(_Float16)b[2]; o[7]=(_Float16)b[3];
    *(half8*)(xs + (size_t)idx * 8) = o;
}

__global__ void conv_w(const float* __restrict__ W_ioux, const float* __restrict__ W_ious,
                       const float* __restrict__ W_fx,   const float* __restrict__ W_fxs,
                       const float* __restrict__ W_fs,   _Float16* __restrict__ wc) {
    int idx = blockIdx.x * blockDim.x + threadIdx.x;
    const int total = NA * KA / 8;
    if (idx >= total) return;
    int n = idx >> 7;
    int col = (idx & 127) * 8;
    const float* src = nullptr;
    if (col < 512) {
        int k = col;
        src = (n < 1536) ? (W_ioux + (size_t)n * 512 + k)
            : (n < 2048) ? (W_fx   + (size_t)(n - 1536) * 512 + k)
                         : (W_fxs  + (size_t)(n - 2048) * 512 + k);
    } else {
        int k = col - 512;
        if (n < 1536)      src = W_ious + (size_t)n * 512 + k;
        else if (n >= 2048) src = W_fs  + (size_t)(n - 2048) * 512 + k;
        // else: zero block (f gate has no sememe term)
    }
    half8 o;
    if (src) {
        f32x4 a = *(const f32x4*)src;
        f32x4 b = *(const f32x4*)(src + 4);
        o[0]=(_Float16)a[0]; o[1]=(_Float16)a[1]; o[2]=(_Float16)a[2]; o[3]=(_Float16)a[3];
        o[4]=(_Float16)b[0]; o[5]=(_Float16)b[1]; o[6]=(_Float16)b[2]; o[7]=(_Float16)b[3];
    } else {
        #pragma unroll
        for (int i = 0; i < 8; ++i) o[i] = (_Float16)0.0f;
    }
    *(half8*)(wc + (size_t)idx * 8) = o;
}

__global__ void conv_wr(const float* __restrict__ W_iouh, const float* __restrict__ W_fh,
                        _Float16* __restrict__ wr) {
    int idx = blockIdx.x * blockDim.x + threadIdx.x;
    const int total = 2048 * 512 / 8;
    if (idx >= total) return;
    int n = idx >> 6;
    int col = (idx & 63) * 8;
    int wgs = n >> 5, loc = n & 31;
    int g = (loc >> 4) * 2 + ((loc >> 3) & 1);
    int m = wgs * 8 + (loc & 7);
    const float* src = (g < 3) ? (W_iouh + ((size_t)(g * 512 + m)) * 512 + col)
                               : (W_fh   + (size_t)m * 512 + col);
    f32x4 a = *(const f32x4*)src;
    f32x4 b = *(const f32x4*)(src + 4);
    half8 o;
    o[0]=(_Float16)a[0]; o[1]=(_Float16)a[1]; o[2]=(_Float16)a[2]; o[3]=(_Float16)a[3];
    o[4]=(_Float16)b[0]; o[5]=(_Float16)b[1]; o[6]=(_Float16)b[2]; o[7]=(_Float16)b[3];
    *(half8*)(wr + (size_t)idx * 8) = o;
}

// h0 -> f16 with 2 LSBs cleared (epoch tag 0): buf0[b][m]
__global__ void conv_h0(const float* __restrict__ h0, unsigned short* __restrict__ hb) {
    int idx = blockIdx.x * blockDim.x + threadIdx.x;
    const int total = B_DIM * M_DIM / 8;
    if (idx >= total) return;
    f32x4 a = *(const f32x4*)(h0 + (size_t)idx * 8);
    f32x4 b = *(const f32x4*)(h0 + (size_t)idx * 8 + 4);
    unsigned short o[8];
    #pragma unroll
    for (int j = 0; j < 4; ++j) {
        _Float16 ha = (_Float16)a[j], hbv = (_Float16)b[j];
        o[j]     = (unsigned short)(__builtin_bit_cast(unsigned short, ha)  & 0xFFFCu);
        o[j + 4] = (unsigned short)(__builtin_bit_cast(unsigned short, hbv) & 0xFFFCu);
    }
    uint32x4 pk;
    pk[0] = o[0] | ((unsigned)o[1] << 16);
    pk[1] = o[2] | ((unsigned)o[3] << 16);
    pk[2] = o[4] | ((unsigned)o[5] << 16);
    pk[3] = o[6] | ((unsigned)o[7] << 16);
    *(uint32x4*)(hb + (size_t)idx * 8) = pk;
}

// ---------------- Phase A: big GEMM + fused epilogue ------------------------

__global__ __launch_bounds__(256, 2)
void gemm_pre(const _Float16* __restrict__ A, const _Float16* __restrict__ W,
              const float* __restrict__ b_ioux, const float* __restrict__ b_iouh,
              const float* __restrict__ b_ious, const float* __restrict__ b_fx,
              const float* __restrict__ b_fh,   const float* __restrict__ b_fxs,
              const float* __restrict__ b_fs,   const float* __restrict__ smc,
              _Float16* __restrict__ pre, _Float16* __restrict__ addc) {
    __shared__ _Float16 As[128 * 64];
    __shared__ _Float16 Bs[128 * 64];

    const int nwg = 2560;
    int orig = blockIdx.x;
    int wgid = (orig & 7) * (nwg >> 3) + (orig >> 3);   // XCD-aware swizzle (2560%8==0)
    const int bx = wgid & 127;       // M tile (128 of them)
    const int by = wgid >> 7;        // N tile (20)
    const int m0 = bx * 128, n0 = by * 128;

    const int tid = threadIdx.x;
    const int wv = tid >> 6, lane = tid & 63;
    const int lr = lane & 15, lq = lane >> 4;
    const int wr = wv >> 1, wc = wv & 1;

    f32x4 acc[4][4];
    #pragma unroll
    for (int i = 0; i < 4; ++i)
        #pragma unroll
        for (int j = 0; j < 4; ++j)
            #pragma unroll
            for (int r = 0; r < 4; ++r) acc[i][j][r] = 0.0f;

    for (int kt = 0; kt < KA / 64; ++kt) {
        const int k0 = kt * 64;
        #pragma unroll
        for (int j = 0; j < 4; ++j) {
            int L = j * 4096 + wv * 1024 + lane * 16;       // linear LDS byte
            int row = L >> 7;
            int colb = (L & 127) ^ ((row & 7) << 4);        // inverse-swizzled source
            const char* ga = (const char*)(A + (size_t)(m0 + row) * KA + k0) + colb;
            __builtin_amdgcn_global_load_lds(
                (const __attribute__((address_space(1))) void*)ga,
                (__attribute__((address_space(3))) void*)((char*)As + j * 4096 + wv * 1024),
                16, 0, 0);
            const char* gb = (const char*)(W + (size_t)(n0 + row) * KA + k0) + colb;
            __builtin_amdgcn_global_load_lds(
                (const __attribute__((address_space(1))) void*)gb,
                (__attribute__((address_space(3))) void*)((char*)Bs + j * 4096 + wv * 1024),
                16, 0, 0);
        }
        __syncthreads();

        half8 af[4][2], bf[4][2];
        #pragma unroll
        for (int f = 0; f < 4; ++f) {
            #pragma unroll
            for (int kk = 0; kk < 2; ++kk) {
                {
                    int row = wr * 64 + f * 16 + lr;
                    int byt = row * 128 + (((kk * 32 + lq * 8) * 2) ^ ((row & 7) << 4));
                    af[f][kk] = *(const half8*)((const char*)As + byt);
                }
                {
                    int row = wc * 64 + f * 16 + lr;
                    int byt = row * 128 + (((kk * 32 + lq * 8) * 2) ^ ((row & 7) << 4));
                    bf[f][kk] = *(const half8*)((const char*)Bs + byt);
                }
            }
        }
        #pragma unroll
        for (int kk = 0; kk < 2; ++kk)
            #pragma unroll
            for (int fi = 0; fi < 4; ++fi)
                #pragma unroll
                for (int fj = 0; fj < 4; ++fj)
                    acc[fi][fj] = __builtin_amdgcn_mfma_f32_16x16x32_f16(
                        af[fi][kk], bf[fj][kk], acc[fi][fj], 0, 0, 0);
        __syncthreads();
    }

    // Epilogue: D layout col=lane&15, row=(lane>>4)*4+reg.
    #pragma unroll
    for (int fi = 0; fi < 4; ++fi) {
        int row0 = m0 + wr * 64 + fi * 16 + lq * 4;  // 4 consecutive tb rows
        int tt = row0 >> 6;
        int b  = row0 & 63;
        #pragma unroll
        for (int fj = 0; fj < 4; ++fj) {
            int col = n0 + wc * 64 + fj * 16 + lr;
            f32x4 v = acc[fi][fj];
            if (col < 2048) {
                int g, mm; float bias;
                if (col < 1536) { g = col >> 9; mm = col & 511;
                                  bias = b_ioux[col] + b_iouh[col] + b_ious[col]; }
                else            { g = 3; mm = col - 1536; bias = b_fx[mm] + b_fh[mm]; }
                half4 hv;
                #pragma unroll
                for (int r = 0; r < 4; ++r) hv[r] = (_Float16)(v[r] + bias);
                *(half4*)(pre + ((((size_t)tt * 4 + g) * 512 + mm) * 64 + b)) = hv;
            } else {
                int mm = col - 2048;
                float bias = b_fxs[mm] + b_fs[mm];
                half4 hv;
                #pragma unroll
                for (int r = 0; r < 4; ++r) {
                    float s  = sigmoidf_fast(v[r] + bias);
                    float sc = smc[((size_t)(tt * 64 + b + r)) * 512 + mm];
                    hv[r] = (_Float16)(s * sc);
                }
                *(half4*)(addc + (((size_t)tt * 512 + mm) * 64 + b)) = hv;
            }
        }
    }
}

// ---------------- Phase B: persistent recurrent kernel ----------------------
// 64 WGs x 256 threads. WG owns m in [wg*8,+8); wave v owns b-tile
// [v*16,+16). Lane l: c8=(l>>3)&1 splits lane pairs l / l^8 into (i,u)/(o,f).
// Weights in registers. h: f16 with tag (step&3) in 2 mantissa LSBs, parity
// double buffer, sc0+sc1. Producer: tagged stores -> vmcnt(0) drain ->
// syncthreads -> per-WG flag. Consumer: SPECULATIVE tagged gather; on tag
// miss: flag-poll backstop then regather (guaranteed fresh post-poll).

// one gather attempt: 16 coherent dwordx4 + vmcnt in ONE asm block; validate
__device__ __forceinline__ bool gather_try(const char* bp, unsigned pat,
                                           half8 (&af)[16]) {
    asm volatile(
        "global_load_dwordx4 %0,  %16, off sc0 sc1\n\t"
        "global_load_dwordx4 %1,  %16, off offset:64 sc0 sc1\n\t"
        "global_load_dwordx4 %2,  %16, off offset:128 sc0 sc1\n\t"
        "global_load_dwordx4 %3,  %16, off offset:192 sc0 sc1\n\t"
        "global_load_dwordx4 %4,  %16, off offset:256 sc0 sc1\n\t"
        "global_load_dwordx4 %5,  %16, off offset:320 sc0 sc1\n\t"
        "global_load_dwordx4 %6,  %16, off offset:384 sc0 sc1\n\t"
        "global_load_dwordx4 %7,  %16, off offset:448 sc0 sc1\n\t"
        "global_load_dwordx4 %8,  %16, off offset:512 sc0 sc1\n\t"
        "global_load_dwordx4 %9,  %16, off offset:576 sc0 sc1\n\t"
        "global_load_dwordx4 %10, %16, off offset:640 sc0 sc1\n\t"
        "global_load_dwordx4 %11, %16, off offset:704 sc0 sc1\n\t"
        "global_load_dwordx4 %12, %16, off offset:768 sc0 sc1\n\t"
        "global_load_dwordx4 %13, %16, off offset:832 sc0 sc1\n\t"
        "global_load_dwordx4 %14, %16, off offset:896 sc0 sc1\n\t"
        "global_load_dwordx4 %15, %16, off offset:960 sc0 sc1\n\t"
        "s_waitcnt vmcnt(0)"
        : "=&v"(af[0]),  "=&v"(af[1]),  "=&v"(af[2]),  "=&v"(af[3]),
          "=&v"(af[4]),  "=&v"(af[5]),  "=&v"(af[6]),  "=&v"(af[7]),
          "=&v"(af[8]),  "=&v"(af[9]),  "=&v"(af[10]), "=&v"(af[11]),
          "=&v"(af[12]), "=&v"(af[13]), "=&v"(af[14]), "=&v"(af[15])
        : "v"(bp)
        : "memory");
    unsigned bad = 0;
    #pragma unroll
    for (int j = 0; j < 16; ++j) {
        uint32x4 dv = __builtin_bit_cast(uint32x4, af[j]);
        #pragma unroll
        for (int d = 0; d < 4; ++d)
            bad |= (dv[d] & 0x00030003u) ^ pat;
    }
    return __all(bad == 0);
}

__global__ __launch_bounds__(256, 1)
void lstm_rec(const _Float16* __restrict__ Wr, const _Float16* __restrict__ pre,
              const _Float16* __restrict__ addc, const float* __restrict__ c0,
              unsigned short* __restrict__ hbuf, float* __restrict__ out,
              int* __restrict__ flags) {
    const int wg = blockIdx.x;
    const int tid = threadIdx.x;
    const int wv = tid >> 6, lane = tid & 63;
    const int lr = lane & 15, lq = lane >> 4;
    const int c8 = (lane >> 3) & 1;
    const int m  = wg * 8 + (lane & 7);
    const int b0 = wv * 16 + lq * 4;

    // recurrent weights -> registers (once)
    half8 bfr[2][16];
    #pragma unroll
    for (int nt = 0; nt < 2; ++nt)
        #pragma unroll
        for (int kk = 0; kk < 16; ++kk)
            bfr[nt][kk] = *(const half8*)(Wr + ((size_t)(wg * 32 + nt * 16 + lr)) * 512
                                          + kk * 32 + lq * 8);

    float c[4];
    #pragma unroll
    for (int r = 0; r < 4; ++r) c[r] = c0[(size_t)(b0 + r) * 512 + m];

    half4 pv[2], av;
    #pragma unroll
    for (int nt = 0; nt < 2; ++nt) {
        int g = nt * 2 + c8;
        pv[nt] = *(const half4*)(pre + (((size_t)0 * 4 + g) * 512 + m) * 64 + b0);
    }
    av = *(const half4*)(addc + ((size_t)0 * 512 + m) * 64 + b0);

    // per-lane gather base: row = wv*16+lr, col-base = lq*8 (f16, 2B)
    const size_t rowoff = ((size_t)(wv * 16 + lr) * 512 + lq * 8) * 2;
    const int* myflag = flags + lane * FLAG_STRIDE;   // lane i polls WG i's flag

    for (int t = 0; t < T_STEPS; ++t) {
        const char* bp = (const char*)hbuf + (size_t)(t & 1) * 65536 + rowoff;
        const unsigned pat = (unsigned)(t & 3) * 0x00010001u;   // expected LSB tag

        // acc init from CURRENT step's pre/addc — BEFORE prefetch clobbers
        f32x4 acc[2];
        #pragma unroll
        for (int nt = 0; nt < 2; ++nt)
            #pragma unroll
            for (int r = 0; r < 4; ++r) acc[nt][r] = (float)pv[nt][r];
        half4 avc = av;

        // prefetch next step's pre/addc (cached; completes under gather RT)
        if (t + 1 < T_STEPS) {
            #pragma unroll
            for (int nt = 0; nt < 2; ++nt) {
                int g = nt * 2 + c8;
                pv[nt] = *(const half4*)(pre + (((size_t)(t + 1) * 4 + g) * 512 + m) * 64 + b0);
            }
            av = *(const half4*)(addc + ((size_t)(t + 1) * 512 + m) * 64 + b0);
        }

        // ---- speculative tagged gather; flag-poll backstop on miss ----
        half8 af[16];
        if (!gather_try(bp, pat, af)) {
            while (true) {
                int v;
                asm volatile("global_load_dword %0, %1, off sc0 sc1\n\t"
                             "s_waitcnt vmcnt(0)"
                             : "=v"(v) : "v"(myflag) : "memory");
                if (__all(v >= t)) break;
                __builtin_amdgcn_s_sleep(1);
            }
            while (!gather_try(bp, pat, af))
                __builtin_amdgcn_s_sleep(1);
        }

        #pragma unroll
        for (int kk = 0; kk < 16; ++kk) {
            acc[0] = __builtin_amdgcn_mfma_f32_16x16x32_f16(af[kk], bfr[0][kk], acc[0], 0, 0, 0);
            acc[1] = __builtin_amdgcn_mfma_f32_16x16x32_f16(af[kk], bfr[1][kk], acc[1], 0, 0, 0);
        }

        float hnew[4];
        #pragma unroll
        for (int r = 0; r < 4; ++r) {
            float raw0 = acc[0][r];   // laneA: i_raw  | laneB: o_raw
            float raw1 = acc[1][r];   // laneA: u_raw  | laneB: f_raw
            float s0 = sigmoidf_fast(raw0);
            float v1 = c8 ? sigmoidf_fast(raw1) : tanhf_fast(raw1);
            float sf = __shfl_xor(v1, 8);               // laneA <- sig(f)
            float cn = s0 * v1 + sf * c[r] + (float)avc[r];   // valid on laneA
            float tc = tanhf_fast(cn);
            float tcx = __shfl_xor(tc, 8);              // laneB <- tanh(c_new)
            if (!c8) c[r] = cn;
            hnew[r] = s0 * tcx;                         // valid on laneB
        }

        if (t == T_STEPS - 1) {
            if (c8) {
                #pragma unroll
                for (int r = 0; r < 4; ++r)
                    out[((size_t)t * B_DIM + b0 + r) * M_DIM + m] = hnew[r];
            }
            size_t base = (size_t)T_STEPS * B_DIM * M_DIM;
            if (!c8) {
                #pragma unroll
                for (int r = 0; r < 4; ++r)
                    out[base + (size_t)(b0 + r) * M_DIM + m] = c[r];
            } else {
                #pragma unroll
                for (int r = 0; r < 4; ++r)
                    out[base + (size_t)B_DIM * M_DIM + (size_t)(b0 + r) * M_DIM + m] = hnew[r];
            }
        } else {
            // publish h^{t+1}: tagged f16 stores -> drain -> syncthreads ->
            // per-WG flag. Drain makes the flag truthful AND paces WG skew.
            unsigned short* hw = hbuf + (size_t)((t + 1) & 1) * 32768;
            const unsigned tag1 = (unsigned)((t + 1) & 3);
            if (c8) {
                #pragma unroll
                for (int r = 0; r < 4; ++r) {
                    _Float16 hv = (_Float16)hnew[r];
                    unsigned u = ((unsigned)__builtin_bit_cast(unsigned short, hv)
                                  & 0xFFFCu) | tag1;
                    asm volatile("global_store_short %0, %1, off sc0 sc1"
                                 :: "v"(hw + (size_t)(b0 + r) * 512 + m), "v"(u)
                                 : "memory");
                }
            }
            asm volatile("s_waitcnt vmcnt(0)" ::: "memory");  // h committed
            __syncthreads();                                  // whole WG committed
            if (tid == 0) {
                unsigned fv = (unsigned)(t + 1);
                asm volatile("global_store_dword %0, %1, off sc0 sc1"
                             :: "v"(flags + wg * FLAG_STRIDE), "v"(fv) : "memory");
            }
            // out[t] stores drain during next gather (normal cached)
            if (c8) {
                #pragma unroll
                for (int r = 0; r < 4; ++r)
                    out[((size_t)t * B_DIM + b0 + r) * M_DIM + m] = hnew[r];
            }
        }
    }
}

// ---------------------------------------------------------------------------

extern "C" void kernel_launch(void* const* d_in, const int* in_sizes, int n_in,
                              void* d_out, int out_size, void* d_ws, size_t ws_size,
                              hipStream_t stream) {
    const float* inputs  = (const float*)d_in[0];
    const float* smc     = (const float*)d_in[1];
    const float* smh     = (const float*)d_in[2];
    const float* c0      = (const float*)d_in[3];
    const float* h0      = (const float*)d_in[4];
    const float* W_ioux  = (const float*)d_in[5];
    const float* b_ioux  = (const float*)d_in[6];
    const float* W_iouh  = (const float*)d_in[7];
    const float* b_iouh  = (const float*)d_in[8];
    const float* W_ious  = (const float*)d_in[9];
    const float* b_ious  = (const float*)d_in[10];
    const float* W_fx    = (const float*)d_in[11];
    const float* b_fx    = (const float*)d_in[12];
    const float* W_fxs   = (const float*)d_in[13];
    const float* b_fxs   = (const float*)d_in[14];
    const float* W_fh    = (const float*)d_in[15];
    const float* b_fh    = (const float*)d_in[16];
    const float* W_fs    = (const float*)d_in[17];
    const float* b_fs    = (const float*)d_in[18];

    char* ws = (char*)d_ws;
    size_t off = 0;
    auto alloc = [&](size_t bytes) {
        char* p = ws + off;
        off = (off + bytes + 255) & ~(size_t)255;
        return p;
    };
    _Float16* XS   = (_Float16*)alloc((size_t)MA * KA * 2);          // 32 MiB
    _Float16* Wc   = (_Float16*)alloc((size_t)NA * KA * 2);          // 5 MiB
    _Float16* Wr   = (_Float16*)alloc((size_t)2048 * 512 * 2);       // 2 MiB
    unsigned short* hb = (unsigned short*)alloc((size_t)2 * B_DIM * M_DIM * 2); // 128 KiB
    _Float16* pre  = (_Float16*)alloc((size_t)T_STEPS * 4 * 512 * 64 * 2); // 64 MiB
    _Float16* addc = (_Float16*)alloc((size_t)T_STEPS * 512 * 64 * 2);     // 16 MiB
    int* flags     = (int*)alloc(NWG_REC * FLAG_STRIDE * sizeof(int));     // 8 KiB
    if (off > ws_size) return;  // insufficient workspace -> visible failure

    hipMemsetAsync(flags, 0, NWG_REC * FLAG_STRIDE * sizeof(int), stream);
    conv_xs <<<MA * KA / 8 / 256, 256, 0, stream>>>(inputs, smh, XS);
    conv_w  <<<NA * KA / 8 / 256, 256, 0, stream>>>(W_ioux, W_ious, W_fx, W_fxs, W_fs, Wc);
    conv_wr <<<2048 * 512 / 8 / 256, 256, 0, stream>>>(W_iouh, W_fh, Wr);
    conv_h0 <<<B_DIM * M_DIM / 8 / 256, 256, 0, stream>>>(h0, hb);
    gemm_pre<<<2560, 256, 0, stream>>>(XS, Wc, b_ioux, b_iouh, b_ious, b_fx, b_fh,
                                       b_fxs, b_fs, smc, pre, addc);
    lstm_rec<<<NWG_REC, 256, 0, stream>>>(Wr, pre, addc, c0, hb, (float*)d_out, flags);
}